// Round 5
// baseline (4230.287 us; speedup 1.0000x reference)
//
#include <hip/hip_runtime.h>

#define DI __device__ __forceinline__

using half8 = __attribute__((ext_vector_type(8))) _Float16;
using f32x4 = __attribute__((ext_vector_type(4))) float;

static constexpr int T_ = 256;
static constexpr int B_ = 32;
static constexpr int H_ = 1024;
static constexpr int V_ = 8192;
static constexpr int GBLK = 256;
static constexpr int TPB = 256;
static constexpr int JPB = 8;
static constexpr int BH = B_ * H_;
static constexpr int LBLK = 128;           // blocks per layer domain
static constexpr int NARR = 16;            // arrival lines per domain
static constexpr int NEP = 8;              // distributed epoch lines
static constexpr int ARRT = LBLK / NARR;   // arrivals per line per round = 8

__device__ _Float16 g_y0[(T_ + 1) * BH];
__device__ _Float16 g_y1[(T_ + 1) * BH];
__device__ _Float16 g_Wt[(size_t)V_ * 4096];  // W_ih0^T fp16: [vocab][4H]
__device__ unsigned g_cnt0[NARR * 32], g_cnt1[NARR * 32];
__device__ unsigned g_ep0[NEP * 32], g_ep1[NEP * 32];
__device__ unsigned g_l0step;

__global__ void init_bar_k() {
  const int i = threadIdx.x;
  if (i < NARR) { g_cnt0[i * 32] = 0u; g_cnt1[i * 32] = 0u; }
  if (i < NEP)  { g_ep0[i * 32] = 0u;  g_ep1[i * 32] = 0u; }
  if (i == 0)   g_l0step = 0u;
}

// ---------------------------------------------------------------------------
// Prepass: W_ih0 (4096 x 8192) f32 -> g_Wt (8192 x 4096) fp16
// ---------------------------------------------------------------------------
__global__ __launch_bounds__(256) void transpose_wih0(const float* __restrict__ in) {
  __shared__ _Float16 t[64][72];
  const int bc = blockIdx.x & 127;
  const int br = blockIdx.x >> 7;
  const int r0 = br * 64, v0 = bc * 64;
  const int tx = threadIdx.x & 15, ty = threadIdx.x >> 4;
#pragma unroll
  for (int it = 0; it < 4; ++it) {
    const int row = ty + it * 16;
    const float4 f = *(const float4*)&in[(size_t)(r0 + row) * V_ + v0 + tx * 4];
    t[tx * 4 + 0][row] = (_Float16)f.x;
    t[tx * 4 + 1][row] = (_Float16)f.y;
    t[tx * 4 + 2][row] = (_Float16)f.z;
    t[tx * 4 + 3][row] = (_Float16)f.w;
  }
  __syncthreads();
#pragma unroll
  for (int it = 0; it < 4; ++it) {
    const int vrow = ty + it * 16;
    union { _Float16 h[4]; unsigned long long u; } o;
    o.h[0] = t[vrow][tx * 4 + 0]; o.h[1] = t[vrow][tx * 4 + 1];
    o.h[2] = t[vrow][tx * 4 + 2]; o.h[3] = t[vrow][tx * 4 + 3];
    *(unsigned long long*)&g_Wt[(size_t)(v0 + vrow) * 4096 + r0 + tx * 4] = o.u;
  }
}

// ---------------------------------------------------------------------------
DI unsigned ldA(const unsigned* p) {
  return __hip_atomic_load(p, __ATOMIC_RELAXED, __HIP_MEMORY_SCOPE_AGENT);
}
DI void stA(unsigned* p, unsigned v) {
  __hip_atomic_store(p, v, __ATOMIC_RELAXED, __HIP_MEMORY_SCOPE_AGENT);
}
DI void addA(unsigned* p) {
  __hip_atomic_fetch_add(p, 1u, __ATOMIC_RELAXED, __HIP_MEMORY_SCOPE_AGENT);
}

DI half8 ld_h16_agent(const _Float16* p) {
  union { unsigned long long u[2]; half8 v; } r;
  r.u[0] = __hip_atomic_load((const unsigned long long*)p, __ATOMIC_RELAXED,
                             __HIP_MEMORY_SCOPE_AGENT);
  r.u[1] = __hip_atomic_load((const unsigned long long*)p + 1, __ATOMIC_RELAXED,
                             __HIP_MEMORY_SCOPE_AGENT);
  return r.v;
}

DI void st_h_agent(_Float16* p, float v) {
  const _Float16 h = (_Float16)v;
  __hip_atomic_store((short*)p, __builtin_bit_cast(short, h), __ATOMIC_RELAXED,
                     __HIP_MEMORY_SCOPE_AGENT);
}

// Wait phase: workers poll a distributed epoch line; the domain master
// aggregates arrivals (and an optional external gate) then publishes.
DI void domain_wait(unsigned* cnt, unsigned* ep, unsigned r, bool isMaster,
                    int epline, const unsigned* gate, unsigned gateval,
                    unsigned* mirror) {
  if (threadIdx.x == 0) {
    if (isMaster) {
      const unsigned tgt = ARRT * r;
      for (;;) {
        bool ok = true;
#pragma unroll
        for (int i = 0; i < NARR; ++i) ok &= (ldA(&cnt[i * 32]) >= tgt);
        if (gate) ok &= (ldA(gate) >= gateval);
        if (ok) break;
        __builtin_amdgcn_s_sleep(1);
      }
#pragma unroll
      for (int i = 0; i < NEP; ++i) stA(&ep[i * 32], r);
      if (mirror) stA(mirror, r);
    } else {
      while (ldA(&ep[epline * 32]) < r) __builtin_amdgcn_s_sleep(2);
    }
  }
  __syncthreads();
}

// Arrive phase: drain stores (syncthreads -> vmcnt(0)), then one RMW.
DI void domain_arrive(unsigned* cnt, int arrline) {
  __syncthreads();
  if (threadIdx.x == 0) addA(&cnt[arrline * 32]);
}

DI float sigmf(float v) { return 1.0f / (1.0f + __expf(-v)); }
DI float tanhf_(float v) { return 1.0f - 2.0f / (__expf(2.0f * v) + 1.0f); }

DI half8 load8_cvt(const float* __restrict__ p) {
  const float4* q = (const float4*)p;
  float4 a = q[0], b = q[1];
  half8 r;
  r[0] = (_Float16)a.x; r[1] = (_Float16)a.y; r[2] = (_Float16)a.z; r[3] = (_Float16)a.w;
  r[4] = (_Float16)b.x; r[5] = (_Float16)b.y; r[6] = (_Float16)b.z; r[7] = (_Float16)b.w;
  return r;
}

// Fused 2-layer persistent LSTM, DECOUPLED sync domains.
// blocks 0-127: layer 0 (sprints ahead, publishes l0_step).
// blocks 128-255: layer 1 (gates on l0_step, lags ~1 step).
__global__ __launch_bounds__(TPB, 1) void lstm_fused(
    const float* __restrict__ Whh0,
    const float* __restrict__ bih0, const float* __restrict__ bhh0,
    const float* __restrict__ Wih1,
    const float* __restrict__ Whh1,
    const float* __restrict__ bih1, const float* __restrict__ bhh1,
    const int* __restrict__ x,
    const float* __restrict__ Hst,
    const float* __restrict__ Cst,
    float* __restrict__ y1out,
    float* __restrict__ outh,
    float* __restrict__ outc)
{
  const int tid = threadIdx.x;
  const int bid = blockIdx.x;
  const int layer = bid >> 7;
  const int kb = bid & 127;
  const int jbase = kb * JPB;
  const int lane = tid & 63;
  const int w = tid >> 6;
  const int m = w & 1;
  const int n = w >> 1;
  const int bb = tid >> 3;
  const int jj = tid & 7;
  const int j = jbase + jj;
  const int arrline = bid & 15;
  const int epline = bid & 7;
  const bool isMaster = (kb == 0);

  __shared__ float gates_lds[32 * 36];
  __shared__ _Float16 wi_lds[32 * 1024];   // layer1: W_ih1 slice, XOR-swizzled

  const float* Whh = layer ? Whh1 : Whh0;
  const float* bih = layer ? bih1 : bih0;
  const float* bhh = layer ? bhh1 : bhh0;
  _Float16* mych = layer ? g_y1 : g_y0;
  unsigned* cnt = layer ? g_cnt1 : g_cnt0;
  unsigned* ep = layer ? g_ep1 : g_ep0;

  st_h_agent(&mych[bb * H_ + j], Hst[layer * BH + bb * H_ + j]);
  float c_reg = Cst[layer * BH + bb * H_ + j];
  float bsum[4];
#pragma unroll
  for (int g = 0; g < 4; ++g) bsum[g] = bih[g * H_ + j] + bhh[g * H_ + j];

  // B-fragment geometry
  const int rowl = lane & 15;
  const int gW = n * 2 + (rowl >> 3);
  const int jW = rowl & 7;
  const int RW = gW * H_ + jbase + jW;
  const int kgrp = (lane >> 4) * 8;
  const int arow = m * 16 + (lane & 15);

  half8 wf[32];   // W_hh fragments, persistent in VGPRs
#pragma unroll
  for (int kk = 0; kk < 32; ++kk)
    wf[kk] = load8_cvt(Whh + (size_t)RW * H_ + kk * 32 + kgrp);

  // layer1: W_ih1 slice -> swizzled LDS (one-time)
  if (layer) {
    for (int idx = tid; idx < 32 * 128; idx += TPB) {
      const int row = idx >> 7;
      const int ch = idx & 127;
      const int g = row >> 3, jw = row & 7;
      half8 v = load8_cvt(Wih1 + (size_t)(g * H_ + jbase + jw) * H_ + ch * 8);
      const unsigned byte = (unsigned)(row * 2048 + ch * 16) ^ (unsigned)((row & 15) << 4);
      *(half8*)((char*)wi_lds + byte) = v;
    }
  }
  const int rowl16 = n * 16 + (lane & 15);
  const unsigned bbase = (unsigned)(rowl16 * 2048 + (lane >> 4) * 16);
  const unsigned bxor = (unsigned)((rowl16 & 15) << 4);
  const char* wib = (const char*)wi_lds;

  // initial arrival: own slot-0 stores drained
  domain_arrive(cnt, arrline);

  float h_last = 0.0f;

  if (layer == 0) {
    // prefetch gather for s=0
    const _Float16* gp = g_Wt + (size_t)x[bb] * 4096 + j;
    float gx0 = (float)gp[0], gx1 = (float)gp[1024];
    float gx2 = (float)gp[2048], gx3 = (float)gp[3072];

    for (int t = 0; t < T_; ++t) {
      domain_wait(cnt, ep, (unsigned)(t + 1), isMaster, epline,
                  nullptr, 0u, &g_l0step);

      const _Float16* hsrc = g_y0 + (size_t)t * BH + arow * H_ + kgrp;
      f32x4 acc0 = {0.f, 0.f, 0.f, 0.f}, acc1 = {0.f, 0.f, 0.f, 0.f};
      half8 a[32];
#pragma unroll
      for (int kk = 0; kk < 32; ++kk) a[kk] = ld_h16_agent(hsrc + kk * 32);
#pragma unroll
      for (int kk = 0; kk < 32; kk += 2) {
        acc0 = __builtin_amdgcn_mfma_f32_16x16x32_f16(a[kk], wf[kk], acc0, 0, 0, 0);
        acc1 = __builtin_amdgcn_mfma_f32_16x16x32_f16(a[kk + 1], wf[kk + 1], acc1, 0, 0, 0);
      }
      acc0 = acc0 + acc1;

      const int gb = m * 16 + (lane >> 4) * 4;
      const int gc = n * 16 + (lane & 15);
#pragma unroll
      for (int r = 0; r < 4; ++r) gates_lds[(gb + r) * 36 + gc] = acc0[r];
      __syncthreads();

      const float gi = gates_lds[bb * 36 + 0 + jj] + gx0 + bsum[0];
      const float gf = gates_lds[bb * 36 + 8 + jj] + gx1 + bsum[1];
      const float gg = gates_lds[bb * 36 + 16 + jj] + gx2 + bsum[2];
      const float go = gates_lds[bb * 36 + 24 + jj] + gx3 + bsum[3];
      const float iv = sigmf(gi), fv = sigmf(gf), gv = tanhf_(gg), ov = sigmf(go);
      c_reg = fv * c_reg + iv * gv;
      const float hv = ov * tanhf_(c_reg);
      h_last = hv;
      st_h_agent(&g_y0[(size_t)(t + 1) * BH + bb * H_ + j], hv);

      if (t + 1 < T_) {
        const _Float16* gp2 = g_Wt + (size_t)x[(t + 1) * B_ + bb] * 4096 + j;
        gx0 = (float)gp2[0]; gx1 = (float)gp2[1024];
        gx2 = (float)gp2[2048]; gx3 = (float)gp2[3072];
      }
      domain_arrive(cnt, arrline);
    }
    // master: aggregate final round so layer 1 can finish
    if (isMaster && tid == 0) {
      const unsigned tgt = ARRT * (unsigned)(T_ + 1);
      for (;;) {
        bool ok = true;
#pragma unroll
        for (int i = 0; i < NARR; ++i) ok &= (ldA(&g_cnt0[i * 32]) >= tgt);
        if (ok) break;
        __builtin_amdgcn_s_sleep(1);
      }
      stA(&g_l0step, (unsigned)(T_ + 1));
    }
  } else {
    for (int t = 0; t < T_; ++t) {
      // round r=t+1; gate: l0_step >= t+2 (y0(t) = g_y0 slot t+1 valid)
      domain_wait(cnt, ep, (unsigned)(t + 1), isMaster, epline,
                  &g_l0step, (unsigned)(t + 2), nullptr);

      const _Float16* hsrc = g_y1 + (size_t)t * BH + arow * H_ + kgrp;
      const _Float16* ysrc = g_y0 + (size_t)(t + 1) * BH + arow * H_ + kgrp;
      f32x4 acc0 = {0.f, 0.f, 0.f, 0.f}, acc1 = {0.f, 0.f, 0.f, 0.f};
      half8 a[32], ay[32];
#pragma unroll
      for (int kk = 0; kk < 32; ++kk) a[kk] = ld_h16_agent(hsrc + kk * 32);
#pragma unroll
      for (int kk = 0; kk < 32; ++kk) ay[kk] = ld_h16_agent(ysrc + kk * 32);
#pragma unroll
      for (int kk = 0; kk < 32; ++kk) {
        acc0 = __builtin_amdgcn_mfma_f32_16x16x32_f16(a[kk], wf[kk], acc0, 0, 0, 0);
        const half8 bi = *(const half8*)(wib + ((bbase + (unsigned)(kk * 64)) ^ bxor));
        acc1 = __builtin_amdgcn_mfma_f32_16x16x32_f16(ay[kk], bi, acc1, 0, 0, 0);
      }
      acc0 = acc0 + acc1;

      const int gb = m * 16 + (lane >> 4) * 4;
      const int gc = n * 16 + (lane & 15);
#pragma unroll
      for (int r = 0; r < 4; ++r) gates_lds[(gb + r) * 36 + gc] = acc0[r];
      __syncthreads();

      const float gi = gates_lds[bb * 36 + 0 + jj] + bsum[0];
      const float gf = gates_lds[bb * 36 + 8 + jj] + bsum[1];
      const float gg = gates_lds[bb * 36 + 16 + jj] + bsum[2];
      const float go = gates_lds[bb * 36 + 24 + jj] + bsum[3];
      const float iv = sigmf(gi), fv = sigmf(gf), gv = tanhf_(gg), ov = sigmf(go);
      c_reg = fv * c_reg + iv * gv;
      const float hv = ov * tanhf_(c_reg);
      h_last = hv;
      st_h_agent(&g_y1[(size_t)(t + 1) * BH + bb * H_ + j], hv);
      y1out[(size_t)t * BH + bb * H_ + j] = hv;

      if (t + 1 < T_) domain_arrive(cnt, arrline);
    }
  }

  outh[layer * BH + bb * H_ + j] = h_last;
  outc[layer * BH + bb * H_ + j] = c_reg;
}

// ---------------------------------------------------------------------------
extern "C" void kernel_launch(void* const* d_in, const int* in_sizes, int n_in,
                              void* d_out, int out_size, void* d_ws, size_t ws_size,
                              hipStream_t stream) {
  (void)in_sizes; (void)n_in; (void)d_ws; (void)ws_size; (void)out_size;

  const int*   x    = (const int*)  d_in[0];
  const float* Hst  = (const float*)d_in[1];
  const float* Cst  = (const float*)d_in[2];
  const float* Wih0 = (const float*)d_in[3];
  const float* Whh0 = (const float*)d_in[4];
  const float* bih0 = (const float*)d_in[5];
  const float* bhh0 = (const float*)d_in[6];
  const float* Wih1 = (const float*)d_in[7];
  const float* Whh1 = (const float*)d_in[8];
  const float* bih1 = (const float*)d_in[9];
  const float* bhh1 = (const float*)d_in[10];

  float* out   = (float*)d_out;
  float* y1out = out;
  float* outh  = out + (size_t)T_ * BH;
  float* outc  = outh + (size_t)2 * BH;

  hipLaunchKernelGGL(init_bar_k, dim3(1), dim3(64), 0, stream);
  hipLaunchKernelGGL(transpose_wih0, dim3(8192), dim3(256), 0, stream, Wih0);
  hipLaunchKernelGGL(lstm_fused, dim3(GBLK), dim3(TPB), 0, stream,
                     Whh0, bih0, bhh0, Wih1, Whh1, bih1, bhh1,
                     x, Hst, Cst, y1out, outh, outc);
}

// Round 6
// 3877.309 us; speedup vs baseline: 1.0910x; 1.0910x over previous
//
#include <hip/hip_runtime.h>

#define DI __device__ __forceinline__

using half8 = __attribute__((ext_vector_type(8))) _Float16;
using f32x4 = __attribute__((ext_vector_type(4))) float;

static constexpr int T_ = 256;
static constexpr int B_ = 32;
static constexpr int H_ = 1024;
static constexpr int V_ = 8192;
static constexpr int GBLK = 256;
static constexpr int TPB = 256;
static constexpr int JPB = 8;
static constexpr int BH = B_ * H_;
static constexpr int LBLK = 128;           // blocks per layer domain
static constexpr int NARR = 16;            // arrival lines per domain
static constexpr int NEP = 8;              // replicated publish lines
static constexpr int ARRT = LBLK / NARR;   // arrivals per line per round

__device__ _Float16 g_y0[(T_ + 1) * BH];
__device__ _Float16 g_y1[(T_ + 1) * BH];
__device__ _Float16 g_Wt[(size_t)V_ * 4096];  // W_ih0^T fp16: [vocab][4H]
__device__ unsigned g_cnt0[NARR * 32], g_cnt1[NARR * 32];
__device__ unsigned g_ep0[NEP * 32], g_ep1[NEP * 32];
__device__ unsigned g_l0s[NEP * 32];          // l0 progress, replicated

__global__ void init_bar_k() {
  const int i = threadIdx.x;
  if (i < NARR) { g_cnt0[i * 32] = 0u; g_cnt1[i * 32] = 0u; }
  if (i < NEP)  { g_ep0[i * 32] = 0u;  g_ep1[i * 32] = 0u; g_l0s[i * 32] = 0u; }
}

// ---------------------------------------------------------------------------
// Prepass: W_ih0 (4096 x 8192) f32 -> g_Wt (8192 x 4096) fp16
// ---------------------------------------------------------------------------
__global__ __launch_bounds__(256) void transpose_wih0(const float* __restrict__ in) {
  __shared__ _Float16 t[64][72];
  const int bc = blockIdx.x & 127;
  const int br = blockIdx.x >> 7;
  const int r0 = br * 64, v0 = bc * 64;
  const int tx = threadIdx.x & 15, ty = threadIdx.x >> 4;
#pragma unroll
  for (int it = 0; it < 4; ++it) {
    const int row = ty + it * 16;
    const float4 f = *(const float4*)&in[(size_t)(r0 + row) * V_ + v0 + tx * 4];
    t[tx * 4 + 0][row] = (_Float16)f.x;
    t[tx * 4 + 1][row] = (_Float16)f.y;
    t[tx * 4 + 2][row] = (_Float16)f.z;
    t[tx * 4 + 3][row] = (_Float16)f.w;
  }
  __syncthreads();
#pragma unroll
  for (int it = 0; it < 4; ++it) {
    const int vrow = ty + it * 16;
    union { _Float16 h[4]; unsigned long long u; } o;
    o.h[0] = t[vrow][tx * 4 + 0]; o.h[1] = t[vrow][tx * 4 + 1];
    o.h[2] = t[vrow][tx * 4 + 2]; o.h[3] = t[vrow][tx * 4 + 3];
    *(unsigned long long*)&g_Wt[(size_t)(v0 + vrow) * 4096 + r0 + tx * 4] = o.u;
  }
}

// ---------------------------------------------------------------------------
DI unsigned ldA(const unsigned* p) {
  return __hip_atomic_load(p, __ATOMIC_RELAXED, __HIP_MEMORY_SCOPE_AGENT);
}
DI void stA(unsigned* p, unsigned v) {
  __hip_atomic_store(p, v, __ATOMIC_RELAXED, __HIP_MEMORY_SCOPE_AGENT);
}
DI void addA(unsigned* p) {
  __hip_atomic_fetch_add(p, 1u, __ATOMIC_RELAXED, __HIP_MEMORY_SCOPE_AGENT);
}
// sc1 write-through stores: lines are never dirty in any L2.
DI void st_h_agent(_Float16* p, float v) {
  const _Float16 h = (_Float16)v;
  __hip_atomic_store((short*)p, __builtin_bit_cast(short, h), __ATOMIC_RELAXED,
                     __HIP_MEMORY_SCOPE_AGENT);
}
DI void st_f_agent(float* p, float v) {
  __hip_atomic_store(p, v, __ATOMIC_RELAXED, __HIP_MEMORY_SCOPE_AGENT);
}

DI float sigmf(float v) { return 1.0f / (1.0f + __expf(-v)); }
DI float tanhf_(float v) { return 1.0f - 2.0f / (__expf(2.0f * v) + 1.0f); }

DI half8 load8_cvt(const float* __restrict__ p) {
  const float4* q = (const float4*)p;
  float4 a = q[0], b = q[1];
  half8 r;
  r[0] = (_Float16)a.x; r[1] = (_Float16)a.y; r[2] = (_Float16)a.z; r[3] = (_Float16)a.w;
  r[4] = (_Float16)b.x; r[5] = (_Float16)b.y; r[6] = (_Float16)b.z; r[7] = (_Float16)b.w;
  return r;
}

// Cooperative stage of one 32x1024 fp16 matrix (64KB) global->LDS,
// XOR-swizzled so MFMA fragment reads are <=2-way bank aliased (free).
DI void stage_mat(_Float16* __restrict__ dstLds, const _Float16* __restrict__ src,
                  int tid) {
#pragma unroll
  for (int i = 0; i < 16; ++i) {
    const int c = tid + i * 256;               // 16B chunk id 0..4095
    const int row = c >> 7;                    // 0..31
    const unsigned byte = ((unsigned)c * 16u) ^ ((unsigned)(row & 7) << 4);
    *(float4*)((char*)dstLds + byte) = *(const float4*)((const char*)src + (size_t)c * 16);
  }
}

// Fused 2-layer persistent LSTM, decoupled domains, LDS-staged h broadcast.
__global__ __launch_bounds__(TPB, 1) void lstm_fused(
    const float* __restrict__ Whh0,
    const float* __restrict__ bih0, const float* __restrict__ bhh0,
    const float* __restrict__ Wih1,
    const float* __restrict__ Whh1,
    const float* __restrict__ bih1, const float* __restrict__ bhh1,
    const int* __restrict__ x,
    const float* __restrict__ Hst,
    const float* __restrict__ Cst,
    float* __restrict__ y1out,
    float* __restrict__ outh,
    float* __restrict__ outc)
{
  const int tid = threadIdx.x;
  const int bid = blockIdx.x;
  const int layer = bid >> 7;
  const int kb = bid & 127;
  const int jbase = kb * JPB;
  const int lane = tid & 63;
  const int w = tid >> 6;
  const int m = w & 1;
  const int n = w >> 1;
  const int bb = tid >> 3;
  const int jj = tid & 7;
  const int j = jbase + jj;
  const int arrline = bid & 15;
  const int epline = bid & 7;
  const bool isMaster = (kb == 0);

  __shared__ _Float16 stage[2][BH];        // 128 KB (L0 uses [0] only)
  __shared__ float gates_lds[32 * 36];     // 4.6 KB  -> forces 1 block/CU

  const float* Whh = layer ? Whh1 : Whh0;
  const float* bih = layer ? bih1 : bih0;
  const float* bhh = layer ? bhh1 : bhh0;
  _Float16* mych = layer ? g_y1 : g_y0;
  unsigned* cnt = layer ? g_cnt1 : g_cnt0;

  st_h_agent(&mych[bb * H_ + j], Hst[layer * BH + bb * H_ + j]);
  float c_reg = Cst[layer * BH + bb * H_ + j];
  float bsum[4];
#pragma unroll
  for (int g = 0; g < 4; ++g) bsum[g] = bih[g * H_ + j] + bhh[g * H_ + j];

  // B-fragment geometry
  const int rowl = lane & 15;
  const int gW = n * 2 + (rowl >> 3);
  const int jW = rowl & 7;
  const int RW = gW * H_ + jbase + jW;
  const int kgrp = (lane >> 4) * 8;
  const int arow = m * 16 + (lane & 15);
  // LDS A-fragment addressing (matches stage_mat swizzle)
  const unsigned abase = (unsigned)(arow * 2048 + (lane >> 4) * 16);
  const unsigned axor = (unsigned)((arow & 7) << 4);

  half8 wf[32];   // W_hh slice, persistent VGPRs
#pragma unroll
  for (int kk = 0; kk < 32; ++kk)
    wf[kk] = load8_cvt(Whh + (size_t)RW * H_ + kk * 32 + kgrp);

  half8 wi[32];   // layer1: W_ih1 slice, persistent VGPRs (1 wave/SIMD -> fits)
  if (layer) {
#pragma unroll
    for (int kk = 0; kk < 32; ++kk)
      wi[kk] = load8_cvt(Wih1 + (size_t)RW * H_ + kk * 32 + kgrp);
  }

  // initial arrival: slot-0 stores drained by the barrier
  __syncthreads();
  if (tid == 0) addA(&cnt[arrline * 32]);

  const int gb = m * 16 + (lane >> 4) * 4;
  const int gc = n * 16 + (lane & 15);
  float h_last = 0.0f;

  if (layer == 0) {
    const _Float16* gp = g_Wt + (size_t)x[bb] * 4096 + j;
    float gx0 = (float)gp[0], gx1 = (float)gp[1024];
    float gx2 = (float)gp[2048], gx3 = (float)gp[3072];

    for (int t = 0; t < T_; ++t) {
      // --- wait round t+1, then one targeted acquire (inv L1/L2) ---
      if (tid == 0) {
        const unsigned r = (unsigned)(t + 1);
        if (isMaster) {
          const unsigned tgt = ARRT * r;
          for (;;) {
            bool ok = true;
#pragma unroll
            for (int i = 0; i < NARR; ++i) ok &= (ldA(&g_cnt0[i * 32]) >= tgt);
            if (ok) break;
            __builtin_amdgcn_s_sleep(1);
          }
#pragma unroll
          for (int i = 0; i < NEP; ++i) { stA(&g_ep0[i * 32], r); stA(&g_l0s[i * 32], r); }
        } else {
          while (ldA(&g_ep0[epline * 32]) < r) __builtin_amdgcn_s_sleep(2);
        }
        __builtin_amdgcn_fence(__ATOMIC_ACQUIRE, "agent");
      }
      __syncthreads();

      // --- stage h(t) into LDS (normal wide loads, post-inv => fresh) ---
      stage_mat(stage[0], g_y0 + (size_t)t * BH, tid);
      __syncthreads();

      f32x4 acc0 = {0.f, 0.f, 0.f, 0.f}, acc1 = {0.f, 0.f, 0.f, 0.f};
#pragma unroll
      for (int kk = 0; kk < 32; kk += 2) {
        const half8 a0 = *(const half8*)((const char*)stage[0] + ((abase + (unsigned)(kk * 64)) ^ axor));
        const half8 a1 = *(const half8*)((const char*)stage[0] + ((abase + (unsigned)((kk + 1) * 64)) ^ axor));
        acc0 = __builtin_amdgcn_mfma_f32_16x16x32_f16(a0, wf[kk], acc0, 0, 0, 0);
        acc1 = __builtin_amdgcn_mfma_f32_16x16x32_f16(a1, wf[kk + 1], acc1, 0, 0, 0);
      }
      acc0 = acc0 + acc1;

#pragma unroll
      for (int r = 0; r < 4; ++r) gates_lds[(gb + r) * 36 + gc] = acc0[r];
      __syncthreads();

      const float gi = gates_lds[bb * 36 + 0 + jj] + gx0 + bsum[0];
      const float gf = gates_lds[bb * 36 + 8 + jj] + gx1 + bsum[1];
      const float gg = gates_lds[bb * 36 + 16 + jj] + gx2 + bsum[2];
      const float go = gates_lds[bb * 36 + 24 + jj] + gx3 + bsum[3];
      const float iv = sigmf(gi), fv = sigmf(gf), gv = tanhf_(gg), ov = sigmf(go);
      c_reg = fv * c_reg + iv * gv;
      const float hv = ov * tanhf_(c_reg);
      h_last = hv;
      st_h_agent(&g_y0[(size_t)(t + 1) * BH + bb * H_ + j], hv);

      if (t + 1 < T_) {
        const _Float16* gp2 = g_Wt + (size_t)x[(t + 1) * B_ + bb] * 4096 + j;
        gx0 = (float)gp2[0]; gx1 = (float)gp2[1024];
        gx2 = (float)gp2[2048]; gx3 = (float)gp2[3072];
      }
      __syncthreads();                       // drain h-store
      if (tid == 0) addA(&g_cnt0[arrline * 32]);
    }
    // final publish so layer 1 can take its last step
    if (isMaster && tid == 0) {
      const unsigned tgt = ARRT * (unsigned)(T_ + 1);
      for (;;) {
        bool ok = true;
#pragma unroll
        for (int i = 0; i < NARR; ++i) ok &= (ldA(&g_cnt0[i * 32]) >= tgt);
        if (ok) break;
        __builtin_amdgcn_s_sleep(1);
      }
#pragma unroll
      for (int i = 0; i < NEP; ++i) stA(&g_l0s[i * 32], (unsigned)(T_ + 1));
    }
  } else {
    for (int t = 0; t < T_; ++t) {
      // --- wait own round t+1 AND l0 progress >= t+2, then acquire ---
      if (tid == 0) {
        const unsigned r = (unsigned)(t + 1);
        if (isMaster) {
          const unsigned tgt = ARRT * r;
          for (;;) {
            bool ok = true;
#pragma unroll
            for (int i = 0; i < NARR; ++i) ok &= (ldA(&g_cnt1[i * 32]) >= tgt);
            if (ok) break;
            __builtin_amdgcn_s_sleep(1);
          }
#pragma unroll
          for (int i = 0; i < NEP; ++i) stA(&g_ep1[i * 32], r);
        } else {
          while (ldA(&g_ep1[epline * 32]) < r) __builtin_amdgcn_s_sleep(2);
        }
        while (ldA(&g_l0s[epline * 32]) < r + 1) __builtin_amdgcn_s_sleep(1);
        __builtin_amdgcn_fence(__ATOMIC_ACQUIRE, "agent");
      }
      __syncthreads();

      // --- stage h1(t) and y0(t) into LDS ---
      stage_mat(stage[0], g_y1 + (size_t)t * BH, tid);
      stage_mat(stage[1], g_y0 + (size_t)(t + 1) * BH, tid);
      __syncthreads();

      f32x4 acc0 = {0.f, 0.f, 0.f, 0.f}, acc1 = {0.f, 0.f, 0.f, 0.f};
#pragma unroll
      for (int kk = 0; kk < 32; ++kk) {
        const unsigned off = (abase + (unsigned)(kk * 64)) ^ axor;
        const half8 av  = *(const half8*)((const char*)stage[0] + off);
        const half8 ayv = *(const half8*)((const char*)stage[1] + off);
        acc0 = __builtin_amdgcn_mfma_f32_16x16x32_f16(av, wf[kk], acc0, 0, 0, 0);
        acc1 = __builtin_amdgcn_mfma_f32_16x16x32_f16(ayv, wi[kk], acc1, 0, 0, 0);
      }
      acc0 = acc0 + acc1;

#pragma unroll
      for (int r = 0; r < 4; ++r) gates_lds[(gb + r) * 36 + gc] = acc0[r];
      __syncthreads();

      const float gi = gates_lds[bb * 36 + 0 + jj] + bsum[0];
      const float gf = gates_lds[bb * 36 + 8 + jj] + bsum[1];
      const float gg = gates_lds[bb * 36 + 16 + jj] + bsum[2];
      const float go = gates_lds[bb * 36 + 24 + jj] + bsum[3];
      const float iv = sigmf(gi), fv = sigmf(gf), gv = tanhf_(gg), ov = sigmf(go);
      c_reg = fv * c_reg + iv * gv;
      const float hv = ov * tanhf_(c_reg);
      h_last = hv;
      st_h_agent(&g_y1[(size_t)(t + 1) * BH + bb * H_ + j], hv);
      st_f_agent(&y1out[(size_t)t * BH + bb * H_ + j], hv);

      if (t + 1 < T_) {
        __syncthreads();
        if (tid == 0) addA(&g_cnt1[arrline * 32]);
      }
    }
  }

  st_f_agent(&outh[layer * BH + bb * H_ + j], h_last);
  st_f_agent(&outc[layer * BH + bb * H_ + j], c_reg);
}

// ---------------------------------------------------------------------------
extern "C" void kernel_launch(void* const* d_in, const int* in_sizes, int n_in,
                              void* d_out, int out_size, void* d_ws, size_t ws_size,
                              hipStream_t stream) {
  (void)in_sizes; (void)n_in; (void)d_ws; (void)ws_size; (void)out_size;

  const int*   x    = (const int*)  d_in[0];
  const float* Hst  = (const float*)d_in[1];
  const float* Cst  = (const float*)d_in[2];
  const float* Wih0 = (const float*)d_in[3];
  const float* Whh0 = (const float*)d_in[4];
  const float* bih0 = (const float*)d_in[5];
  const float* bhh0 = (const float*)d_in[6];
  const float* Wih1 = (const float*)d_in[7];
  const float* Whh1 = (const float*)d_in[8];
  const float* bih1 = (const float*)d_in[9];
  const float* bhh1 = (const float*)d_in[10];

  float* out   = (float*)d_out;
  float* y1out = out;
  float* outh  = out + (size_t)T_ * BH;
  float* outc  = outh + (size_t)2 * BH;

  hipLaunchKernelGGL(init_bar_k, dim3(1), dim3(64), 0, stream);
  hipLaunchKernelGGL(transpose_wih0, dim3(8192), dim3(256), 0, stream, Wih0);
  hipLaunchKernelGGL(lstm_fused, dim3(GBLK), dim3(TPB), 0, stream,
                     Whh0, bih0, bhh0, Wih1, Whh1, bih1, bhh1,
                     x, Hst, Cst, y1out, outh, outc);
}

// Round 9
// 1471.299 us; speedup vs baseline: 2.8752x; 2.6353x over previous
//
#include <hip/hip_runtime.h>

#define DI __device__ __forceinline__

using half8 = __attribute__((ext_vector_type(8))) _Float16;
using f32x4 = __attribute__((ext_vector_type(4))) float;
using ull = unsigned long long;

static constexpr int T_ = 256;
static constexpr int B_ = 32;
static constexpr int H_ = 1024;
static constexpr int V_ = 8192;
static constexpr int TPB = 256;
static constexpr int BH = B_ * H_;        // 32768 elems
static constexpr int GX = 4 * H_;         // 4096 gate rows
static constexpr int TC = 8;              // helper chunk (steps)
static constexpr int NCH = T_ / TC;       // 32 chunks
static constexpr int GUARD = 60000;       // poll cap: bounded failure, no timeout

// ---- device state (re-initialized every launch by init kernel) ----
__device__ _Float16 g_y0loc[(T_ + 1) * BH];         // L0 h chain (XCD0 L2 traffic)
__device__ _Float16 g_y1loc[(T_ + 1) * BH];         // L1 h chain (XCD1 L2 traffic)
__device__ ull g_y0pub[(size_t)(T_ + 1) * BH / 4];  // L0 h published (sc1, LLC)
__device__ _Float16 g_ggx[(size_t)T_ * B_ * GX];    // helpers: y0@Wih1^T (no bias)
__device__ _Float16 g_Wt[(size_t)V_ * GX];          // W_ih0^T fp16: [vocab][4H]
__device__ unsigned g_xcdcnt[8 * 32];               // per-XCD election tickets
__device__ unsigned g_heltick[32];                  // global helper ticket
__device__ unsigned g_arr0[4 * 32], g_arr1[4 * 32]; // arrival lines (sc1)
__device__ unsigned g_ep0[32], g_ep1[32];           // epoch lines (sc1)
__device__ unsigned g_l0prog[32];                   // y0pub slots 0..P valid (sc1)
__device__ unsigned g_chunk[NCH * 32];              // helper chunk arrivals (sc1)

__global__ void init_bar_k() {
  const int i = threadIdx.x;   // 1024 threads
  if (i < 256) g_xcdcnt[i] = 0u;
  if (i < 128) { g_arr0[i] = 0u; g_arr1[i] = 0u; }
  if (i < 32)  { g_ep0[i] = 0u; g_ep1[i] = 0u; g_l0prog[i] = 0u; g_heltick[i] = 0u; }
  g_chunk[i] = 0u;             // NCH*32 = 1024
}

// ---------------------------------------------------------------------------
// Prepass: W_ih0 (4096 x 8192) f32 -> g_Wt (8192 x 4096) fp16
// ---------------------------------------------------------------------------
__global__ __launch_bounds__(256) void transpose_wih0(const float* __restrict__ in) {
  __shared__ _Float16 t[64][72];
  const int bc = blockIdx.x & 127;
  const int br = blockIdx.x >> 7;
  const int r0 = br * 64, v0 = bc * 64;
  const int tx = threadIdx.x & 15, ty = threadIdx.x >> 4;
#pragma unroll
  for (int it = 0; it < 4; ++it) {
    const int row = ty + it * 16;
    const float4 f = *(const float4*)&in[(size_t)(r0 + row) * V_ + v0 + tx * 4];
    t[tx * 4 + 0][row] = (_Float16)f.x;
    t[tx * 4 + 1][row] = (_Float16)f.y;
    t[tx * 4 + 2][row] = (_Float16)f.z;
    t[tx * 4 + 3][row] = (_Float16)f.w;
  }
  __syncthreads();
#pragma unroll
  for (int it = 0; it < 4; ++it) {
    const int vrow = ty + it * 16;
    union { _Float16 h[4]; ull u; } o;
    o.h[0] = t[vrow][tx * 4 + 0]; o.h[1] = t[vrow][tx * 4 + 1];
    o.h[2] = t[vrow][tx * 4 + 2]; o.h[3] = t[vrow][tx * 4 + 3];
    *(ull*)&g_Wt[(size_t)(v0 + vrow) * GX + r0 + tx * 4] = o.u;
  }
}

// ---------------------------------------------------------------------------
// All sync via agent-scope (sc1) atomics — the primitive proven in R2-R6.
DI unsigned ld_ag(const unsigned* p) { return __hip_atomic_load(p, __ATOMIC_RELAXED, __HIP_MEMORY_SCOPE_AGENT); }
DI void st_ag(unsigned* p, unsigned v) { __hip_atomic_store(p, v, __ATOMIC_RELAXED, __HIP_MEMORY_SCOPE_AGENT); }
DI unsigned add_ag(unsigned* p) { return __hip_atomic_fetch_add(p, 1u, __ATOMIC_RELAXED, __HIP_MEMORY_SCOPE_AGENT); }
DI void st_ag64(ull* p, ull v) { __hip_atomic_store(p, v, __ATOMIC_RELAXED, __HIP_MEMORY_SCOPE_AGENT); }

DI float sigmf(float v) { return 1.0f / (1.0f + __expf(-v)); }
DI float tanhf_(float v) { return 1.0f - 2.0f / (__expf(2.0f * v) + 1.0f); }

DI half8 load8_cvt(const float* __restrict__ p) {
  const float4* q = (const float4*)p;
  float4 a = q[0], b = q[1];
  half8 r;
  r[0] = (_Float16)a.x; r[1] = (_Float16)a.y; r[2] = (_Float16)a.z; r[3] = (_Float16)a.w;
  r[4] = (_Float16)b.x; r[5] = (_Float16)b.y; r[6] = (_Float16)b.z; r[7] = (_Float16)b.w;
  return r;
}

// stage one 32x1024 fp16 matrix (64KB) global->LDS via global_load_lds,
// swizzle applied by permuting the SOURCE chunks (dest stays linear, m201).
DI void stage_h(_Float16* ldsbase, const _Float16* src, int w) {
  const int lane = (int)(threadIdx.x & 63);
#pragma unroll
  for (int i = 0; i < 16; ++i) {
    const int d = (w * 16 + i) * 64 + lane;          // dest 16B chunk id
    const int row = d >> 7;
    const int cir = d & 127;
    const int sc = row * 128 + (cir ^ (row & 7));    // source chunk
    __builtin_amdgcn_global_load_lds(
        (const __attribute__((address_space(1))) void*)((const char*)src + (size_t)sc * 16),
        (__attribute__((address_space(3))) void*)((char*)ldsbase + (size_t)(w * 16 + i) * 1024),
        16, 0, 0);
  }
}

// swizzled A-fragment read from staged LDS
DI half8 lds_a(const _Float16* stg, int arow, int kk, int kgb) {
  unsigned off = (unsigned)(arow * 2048 + kk * 64 + kgb);
  off ^= (unsigned)((arow & 7) << 4);
  return *(const half8*)((const char*)stg + off);
}

// ---------------------------------------------------------------------------
__global__ __launch_bounds__(TPB, 1) void lstm_fused(
    const float* __restrict__ Whh0,
    const float* __restrict__ bih0, const float* __restrict__ bhh0,
    const float* __restrict__ Wih1,
    const float* __restrict__ Whh1,
    const float* __restrict__ bih1, const float* __restrict__ bhh1,
    const int* __restrict__ x,
    const float* __restrict__ Hst,
    const float* __restrict__ Cst,
    float* __restrict__ y1out,
    float* __restrict__ outh,
    float* __restrict__ outc)
{
  const int tid = threadIdx.x;
  const int lane = tid & 63;
  const int w = tid >> 6;

  __shared__ _Float16 stage_s[BH];       // 64 KB
  __shared__ float gates_s[32 * 132];    // 16.9 KB -> 81KB total -> 1 block/CU
  __shared__ unsigned sh_xcc, sh_rank;

  if (tid == 0) {
    unsigned xc;
    asm volatile("s_getreg_b32 %0, hwreg(HW_REG_XCC_ID)" : "=s"(xc));
    xc &= 7u;
    sh_xcc = xc;
    sh_rank = __hip_atomic_fetch_add(&g_xcdcnt[xc * 32], 1u,
                                     __ATOMIC_RELAXED, __HIP_MEMORY_SCOPE_AGENT);
  }
  __syncthreads();
  const unsigned xcc = sh_xcc;
  const unsigned rank = sh_rank;

  const int kgrp = (lane >> 4) * 8;      // halfs
  const int kgb = (lane >> 4) * 16;      // bytes

  // =========================== recurrence role ===========================
  if (xcc <= 1u && rank < 32u) {
    const bool isL1 = (xcc == 1u);
    const int jbase = (int)rank * 32;    // this block's 32 hidden dims
    const float* Whh = isL1 ? Whh1 : Whh0;
    const float* bih = isL1 ? bih1 : bih0;
    const float* bhh = isL1 ? bhh1 : bhh0;
    _Float16* yloc = isL1 ? g_y1loc : g_y0loc;
    unsigned* arr = isL1 ? g_arr1 : g_arr0;
    unsigned* ep = isL1 ? g_ep1 : g_ep0;
    const int arrline = (int)(rank & 3);   // 4 lines x 8 blocks

    // W_hh fragments -> VGPRs (wave w == gate w; two 16-dim N-tiles)
    half8 wf0[32], wf1[32];
    {
      const int rw0 = w * H_ + jbase + (lane & 15);
      const int rw1 = rw0 + 16;
#pragma unroll
      for (int kk = 0; kk < 32; ++kk) {
        wf0[kk] = load8_cvt(Whh + (size_t)rw0 * H_ + kk * 32 + kgrp);
        wf1[kk] = load8_cvt(Whh + (size_t)rw1 * H_ + kk * 32 + kgrp);
      }
    }

    const int b = tid >> 3;
    const int d0 = (tid & 7) * 4;
    const int j0 = jbase + d0;

    float bs[4][4];
#pragma unroll
    for (int g = 0; g < 4; ++g)
#pragma unroll
      for (int dd = 0; dd < 4; ++dd)
        bs[g][dd] = bih[g * H_ + j0 + dd] + bhh[g * H_ + j0 + dd];

    float cc[4], hf[4];
    {
      const float4 hi = *(const float4*)&Hst[(isL1 ? BH : 0) + b * H_ + j0];
      const float4 ci = *(const float4*)&Cst[(isL1 ? BH : 0) + b * H_ + j0];
      cc[0] = ci.x; cc[1] = ci.y; cc[2] = ci.z; cc[3] = ci.w;
      hf[0] = hi.x; hf[1] = hi.y; hf[2] = hi.z; hf[3] = hi.w;
    }
    union { _Float16 h[4]; ull u; } pk;
#pragma unroll
    for (int dd = 0; dd < 4; ++dd) pk.h[dd] = (_Float16)hf[dd];
    ull hv_keep = pk.u;
    *(ull*)&yloc[(size_t)b * H_ + j0] = hv_keep;     // slot 0 (plain, local L2)

    __syncthreads();                                  // drain slot-0 stores
    if (tid == 0) add_ag(&arr[arrline * 32]);         // round 1 arrival

    float h_last = hf[0];  // placeholder; real value tracked below
    (void)h_last;

    for (int t = 0; t < T_; ++t) {
      // input-side gates: prefetch BEFORE the wait (independent of h)
      ull gxu[4];
      if (!isL1) {
        const int xv = x[t * B_ + b];
        const _Float16* gp = g_Wt + (size_t)xv * GX + j0;
#pragma unroll
        for (int g = 0; g < 4; ++g) gxu[g] = *(const ull*)(gp + g * H_);
      }

      // ---- wait phase (sc1) ----
      if (tid == 0) {
        const unsigned r = (unsigned)(t + 1);
        int guard = 0;
        if (rank == 0u) {
          const unsigned tgt = 8u * r;
          for (;;) {
            bool ok = true;
#pragma unroll
            for (int i = 0; i < 4; ++i) ok &= (ld_ag(&arr[i * 32]) >= tgt);
            if (isL1 && ok && (t & (TC - 1)) == 0)
              ok &= (ld_ag(&g_chunk[(t / TC) * 32]) >= 128u);
            if (ok) break;
            __builtin_amdgcn_s_sleep(1);
            if (++guard > GUARD) break;
          }
          st_ag(ep, r);
          if (!isL1 && t >= 1) st_ag(g_l0prog, (unsigned)(t - 1));
        } else {
          while (ld_ag(ep) < r) {
            __builtin_amdgcn_s_sleep(1);
            if (++guard > GUARD) break;
          }
        }
      }
      __syncthreads();

      // L1: input gates from helper-precomputed ggx (sc1-written; fresh lines)
      if (isL1) {
        const _Float16* gp = g_ggx + ((size_t)t * B_ + b) * GX + j0;
#pragma unroll
        for (int g = 0; g < 4; ++g) gxu[g] = *(const ull*)(gp + g * H_);
      }

      // publish previous h slot (L0 only, sc1 -> LLC; drains at step end)
      if (!isL1)
        st_ag64(&g_y0pub[((size_t)t * BH + b * H_ + j0) >> 2], hv_keep);

      // stage h(t) 64KB -> LDS (plain loads, same-XCD L2 hits)
      stage_h(stage_s, yloc + (size_t)t * BH, w);
      __syncthreads();

      // MFMA: 2 M-tiles x 2 N-tiles x K=1024
      f32x4 a00 = {0.f,0.f,0.f,0.f}, a01 = {0.f,0.f,0.f,0.f};
      f32x4 a10 = {0.f,0.f,0.f,0.f}, a11 = {0.f,0.f,0.f,0.f};
#pragma unroll
      for (int kk = 0; kk < 32; ++kk) {
        const half8 A0 = lds_a(stage_s, (lane & 15), kk, kgb);
        const half8 A1 = lds_a(stage_s, 16 + (lane & 15), kk, kgb);
        a00 = __builtin_amdgcn_mfma_f32_16x16x32_f16(A0, wf0[kk], a00, 0, 0, 0);
        a01 = __builtin_amdgcn_mfma_f32_16x16x32_f16(A0, wf1[kk], a01, 0, 0, 0);
        a10 = __builtin_amdgcn_mfma_f32_16x16x32_f16(A1, wf0[kk], a10, 0, 0, 0);
        a11 = __builtin_amdgcn_mfma_f32_16x16x32_f16(A1, wf1[kk], a11, 0, 0, 0);
      }

      // gate exchange: rows = batch (M), cols = gate w * 32 + local dim (N)
      {
        const int colb = w * 32 + (lane & 15);
        const int rowb = (lane >> 4) * 4;
#pragma unroll
        for (int r = 0; r < 4; ++r) {
          gates_s[(rowb + r) * 132 + colb]           = a00[r];
          gates_s[(rowb + r) * 132 + colb + 16]      = a01[r];
          gates_s[(16 + rowb + r) * 132 + colb]      = a10[r];
          gates_s[(16 + rowb + r) * 132 + colb + 16] = a11[r];
        }
      }
      __syncthreads();

      // activation
      float gate[4][4];
#pragma unroll
      for (int g = 0; g < 4; ++g) {
        const _Float16* gh = (const _Float16*)&gxu[g];
#pragma unroll
        for (int dd = 0; dd < 4; ++dd)
          gate[g][dd] = gates_s[b * 132 + g * 32 + d0 + dd] + (float)gh[dd] + bs[g][dd];
      }
#pragma unroll
      for (int dd = 0; dd < 4; ++dd) {
        const float iv = sigmf(gate[0][dd]), fv = sigmf(gate[1][dd]);
        const float gv = tanhf_(gate[2][dd]), ov = sigmf(gate[3][dd]);
        cc[dd] = fv * cc[dd] + iv * gv;
        hf[dd] = ov * tanhf_(cc[dd]);
        pk.h[dd] = (_Float16)hf[dd];
      }
      hv_keep = pk.u;
      *(ull*)&yloc[(size_t)(t + 1) * BH + b * H_ + j0] = hv_keep;   // plain/local
      if (isL1)
        *(float4*)&y1out[(size_t)t * BH + b * H_ + j0] =
            make_float4(hf[0], hf[1], hf[2], hf[3]);

      __syncthreads();                      // drain stores (incl. sc1 publish)
      if (tid == 0) add_ag(&arr[arrline * 32]);
    }

    // L0 epilogue: publish final slot, then final progress (=T)
    if (!isL1) {
      st_ag64(&g_y0pub[((size_t)T_ * BH + b * H_ + j0) >> 2], hv_keep);
      __syncthreads();
      if (tid == 0) add_ag(&g_arr0[arrline * 32]);   // round T+2
      if (rank == 0u && tid == 0) {
        const unsigned tgt = 8u * (unsigned)(T_ + 2);
        int guard = 0;
        for (;;) {
          bool ok = true;
#pragma unroll
          for (int i = 0; i < 4; ++i) ok &= (ld_ag(&g_arr0[i * 32]) >= tgt);
          if (ok) break;
          __builtin_amdgcn_s_sleep(1);
          if (++guard > GUARD) break;
        }
        st_ag(g_l0prog, (unsigned)T_);
      }
    }

    *(float4*)&outh[(isL1 ? BH : 0) + b * H_ + j0] = make_float4(hf[0], hf[1], hf[2], hf[3]);
    *(float4*)&outc[(isL1 ? BH : 0) + b * H_ + j0] = make_float4(cc[0], cc[1], cc[2], cc[3]);
    return;
  }

  // ============================ helper role ==============================
  // Any non-recurrence block takes a global ticket; first 128 work.
  __shared__ unsigned sh_hid;
  if (tid == 0) sh_hid = add_ag(g_heltick);
  __syncthreads();
  const unsigned hid = sh_hid;
  if (hid >= 128u) return;

  half8 wih0[32], wih1[32];
  {
    const int rw0 = (int)hid * 32 + (lane & 15);
    const int rw1 = rw0 + 16;
#pragma unroll
    for (int kk = 0; kk < 32; ++kk) {
      wih0[kk] = load8_cvt(Wih1 + (size_t)rw0 * H_ + kk * 32 + kgrp);
      wih1[kk] = load8_cvt(Wih1 + (size_t)rw1 * H_ + kk * 32 + kgrp);
    }
  }
  const int cg0 = (int)hid * 32 + (lane & 15);
  const int cg1 = cg0 + 16;
  const _Float16* y0pub = (const _Float16*)g_y0pub;

  for (int c = 0; c < NCH; ++c) {
    if (tid == 0) {
      int guard = 0;
      while (ld_ag(g_l0prog) < (unsigned)(c * TC + TC)) {
        __builtin_amdgcn_s_sleep(4);
        if (++guard > GUARD) break;
      }
    }
    __syncthreads();
    const int t0 = c * TC;

#pragma unroll 1
    for (int mt = 0; mt < 4; ++mt) {
      const int arow = w * 64 + mt * 16 + (lane & 15);        // 0..255
      const _Float16* asrc = y0pub + (size_t)(t0 + (arow >> 5) + 1) * BH +
                             (size_t)(arow & 31) * H_ + kgrp;
      f32x4 e0 = {0.f,0.f,0.f,0.f}, e1 = {0.f,0.f,0.f,0.f};
#pragma unroll
      for (int kk = 0; kk < 32; ++kk) {
        const half8 a = *(const half8*)(asrc + kk * 32);
        e0 = __builtin_amdgcn_mfma_f32_16x16x32_f16(a, wih0[kk], e0, 0, 0, 0);
        e1 = __builtin_amdgcn_mfma_f32_16x16x32_f16(a, wih1[kk], e1, 0, 0, 0);
      }
      const int mrow = w * 64 + mt * 16 + (lane >> 4) * 4;
#pragma unroll
      for (int r = 0; r < 4; ++r) {
        const int m = mrow + r;
        const int tt = t0 + (m >> 5);
        const int bb = m & 31;
        const _Float16 v0 = (_Float16)e0[r];    // raw GEMM; bias added by L1
        const _Float16 v1 = (_Float16)e1[r];
        __hip_atomic_store((short*)&g_ggx[((size_t)tt * B_ + bb) * GX + cg0],
                           __builtin_bit_cast(short, v0),
                           __ATOMIC_RELAXED, __HIP_MEMORY_SCOPE_AGENT);
        __hip_atomic_store((short*)&g_ggx[((size_t)tt * B_ + bb) * GX + cg1],
                           __builtin_bit_cast(short, v1),
                           __ATOMIC_RELAXED, __HIP_MEMORY_SCOPE_AGENT);
      }
    }
    __syncthreads();                       // drain sc1 stores
    if (tid == 0) add_ag(&g_chunk[c * 32]);
  }
}

// ---------------------------------------------------------------------------
extern "C" void kernel_launch(void* const* d_in, const int* in_sizes, int n_in,
                              void* d_out, int out_size, void* d_ws, size_t ws_size,
                              hipStream_t stream) {
  (void)in_sizes; (void)n_in; (void)d_ws; (void)ws_size; (void)out_size;

  const int*   x    = (const int*)  d_in[0];
  const float* Hst  = (const float*)d_in[1];
  const float* Cst  = (const float*)d_in[2];
  const float* Wih0 = (const float*)d_in[3];
  const float* Whh0 = (const float*)d_in[4];
  const float* bih0 = (const float*)d_in[5];
  const float* bhh0 = (const float*)d_in[6];
  const float* Wih1 = (const float*)d_in[7];
  const float* Whh1 = (const float*)d_in[8];
  const float* bih1 = (const float*)d_in[9];
  const float* bhh1 = (const float*)d_in[10];

  float* out   = (float*)d_out;
  float* y1out = out;
  float* outh  = out + (size_t)T_ * BH;
  float* outc  = outh + (size_t)2 * BH;

  hipLaunchKernelGGL(init_bar_k, dim3(1), dim3(1024), 0, stream);
  hipLaunchKernelGGL(transpose_wih0, dim3(8192), dim3(256), 0, stream, Wih0);
  hipLaunchKernelGGL(lstm_fused, dim3(256), dim3(TPB), 0, stream,
                     Whh0, bih0, bhh0, Wih1, Whh1, bih1, bhh1,
                     x, Hst, Cst, y1out, outh, outc);
}

// Round 10
// 1416.550 us; speedup vs baseline: 2.9863x; 1.0386x over previous
//
#include <hip/hip_runtime.h>

#define DI __device__ __forceinline__

using half8 = __attribute__((ext_vector_type(8))) _Float16;
using f32x4 = __attribute__((ext_vector_type(4))) float;
using ull = unsigned long long;

static constexpr int T_ = 256;
static constexpr int B_ = 32;
static constexpr int H_ = 1024;
static constexpr int V_ = 8192;
static constexpr int TPB = 256;
static constexpr int BH = B_ * H_;        // 32768 elems
static constexpr int GX = 4 * H_;         // 4096 gate rows
static constexpr int TC = 8;              // helper chunk (steps)
static constexpr int NCH = T_ / TC;       // 32 chunks
static constexpr int GUARD = 60000;       // poll cap: bounded failure, no timeout

// ---- device state (re-initialized every launch by init kernel) ----
__device__ _Float16 g_y0loc[(T_ + 1) * BH];         // L0 h chain (XCD0 L2 traffic)
__device__ _Float16 g_y1loc[(T_ + 1) * BH];         // L1 h chain (XCD1 L2 traffic)
__device__ ull g_y0pub[(size_t)(T_ + 1) * BH / 4];  // L0 h published (sc1)
__device__ ull g_ggx[(size_t)T_ * B_ * GX / 4];     // helpers: y0@Wih1^T (no bias)
__device__ _Float16 g_Wt[(size_t)V_ * GX];          // W_ih0^T fp16: [vocab][4H]
__device__ unsigned g_xcdcnt[8 * 32];               // per-XCD election tickets
__device__ unsigned g_heltick[32];                  // global helper ticket
__device__ unsigned g_slot0[32 * 8];                // per-block round slots (sc1)
__device__ unsigned g_slot1[32 * 8];
__device__ unsigned g_l0prog[32];                   // y0pub slots 0..P valid (sc1)
__device__ unsigned g_chunk[NCH * 32];              // helper chunk arrivals (sc1)

__global__ void init_bar_k() {
  const int i = threadIdx.x;   // 1024 threads
  if (i < 256) { g_xcdcnt[i] = 0u; g_slot0[i] = 0u; g_slot1[i] = 0u; }
  if (i < 32)  { g_l0prog[i] = 0u; g_heltick[i] = 0u; }
  g_chunk[i] = 0u;             // NCH*32 = 1024
}

// ---------------------------------------------------------------------------
// Prepass: W_ih0 (4096 x 8192) f32 -> g_Wt (8192 x 4096) fp16
// ---------------------------------------------------------------------------
__global__ __launch_bounds__(256) void transpose_wih0(const float* __restrict__ in) {
  __shared__ _Float16 t[64][72];
  const int bc = blockIdx.x & 127;
  const int br = blockIdx.x >> 7;
  const int r0 = br * 64, v0 = bc * 64;
  const int tx = threadIdx.x & 15, ty = threadIdx.x >> 4;
#pragma unroll
  for (int it = 0; it < 4; ++it) {
    const int row = ty + it * 16;
    const float4 f = *(const float4*)&in[(size_t)(r0 + row) * V_ + v0 + tx * 4];
    t[tx * 4 + 0][row] = (_Float16)f.x;
    t[tx * 4 + 1][row] = (_Float16)f.y;
    t[tx * 4 + 2][row] = (_Float16)f.z;
    t[tx * 4 + 3][row] = (_Float16)f.w;
  }
  __syncthreads();
#pragma unroll
  for (int it = 0; it < 4; ++it) {
    const int vrow = ty + it * 16;
    union { _Float16 h[4]; ull u; } o;
    o.h[0] = t[vrow][tx * 4 + 0]; o.h[1] = t[vrow][tx * 4 + 1];
    o.h[2] = t[vrow][tx * 4 + 2]; o.h[3] = t[vrow][tx * 4 + 3];
    *(ull*)&g_Wt[(size_t)(v0 + vrow) * GX + r0 + tx * 4] = o.u;
  }
}

// ---------------------------------------------------------------------------
DI unsigned ld_ag(const unsigned* p) { return __hip_atomic_load(p, __ATOMIC_RELAXED, __HIP_MEMORY_SCOPE_AGENT); }
DI void st_ag(unsigned* p, unsigned v) { __hip_atomic_store(p, v, __ATOMIC_RELAXED, __HIP_MEMORY_SCOPE_AGENT); }
DI unsigned add_ag(unsigned* p) { return __hip_atomic_fetch_add(p, 1u, __ATOMIC_RELAXED, __HIP_MEMORY_SCOPE_AGENT); }
DI void st_ag64(ull* p, ull v) { __hip_atomic_store(p, v, __ATOMIC_RELAXED, __HIP_MEMORY_SCOPE_AGENT); }
DI ull ld_ag64(const ull* p) { return __hip_atomic_load(p, __ATOMIC_RELAXED, __HIP_MEMORY_SCOPE_AGENT); }

DI float sigmf(float v) { return 1.0f / (1.0f + __expf(-v)); }
DI float tanhf_(float v) { return 1.0f - 2.0f / (__expf(2.0f * v) + 1.0f); }

DI half8 load8_cvt(const float* __restrict__ p) {
  const float4* q = (const float4*)p;
  float4 a = q[0], b = q[1];
  half8 r;
  r[0] = (_Float16)a.x; r[1] = (_Float16)a.y; r[2] = (_Float16)a.z; r[3] = (_Float16)a.w;
  r[4] = (_Float16)b.x; r[5] = (_Float16)b.y; r[6] = (_Float16)b.z; r[7] = (_Float16)b.w;
  return r;
}

// In-wave all-peer wait: lane i polls slot i (one vector sc1 load per iter);
// lane 32 optionally polls an extra gate. Reconverges when all satisfied.
DI void slot_wait(unsigned* slots, unsigned r, const unsigned* extra,
                  unsigned extraTgt) {
  const int tid = threadIdx.x;
  if (tid < 64) {
    if (tid < 32) {
      int guard = 0;
      while (ld_ag(&slots[tid * 8]) < r) {
        __builtin_amdgcn_s_sleep(1);
        if (++guard > GUARD) break;
      }
    } else if (tid == 32 && extra) {
      int guard = 0;
      while (ld_ag(extra) < extraTgt) {
        __builtin_amdgcn_s_sleep(1);
        if (++guard > GUARD) break;
      }
    }
  }
  __syncthreads();
}

// stage one 32x1024 fp16 matrix (64KB) global->LDS via global_load_lds,
// swizzle applied by permuting the SOURCE chunks (dest stays linear, m201).
DI void stage_h(_Float16* ldsbase, const _Float16* src, int w) {
  const int lane = (int)(threadIdx.x & 63);
#pragma unroll
  for (int i = 0; i < 16; ++i) {
    const int d = (w * 16 + i) * 64 + lane;          // dest 16B chunk id
    const int row = d >> 7;
    const int cir = d & 127;
    const int sc = row * 128 + (cir ^ (row & 7));    // source chunk
    __builtin_amdgcn_global_load_lds(
        (const __attribute__((address_space(1))) void*)((const char*)src + (size_t)sc * 16),
        (__attribute__((address_space(3))) void*)((char*)ldsbase + (size_t)(w * 16 + i) * 1024),
        16, 0, 0);
  }
}

// swizzled A-fragment read from staged LDS
DI half8 lds_a(const _Float16* stg, int arow, int kk, int kgb) {
  unsigned off = (unsigned)(arow * 2048 + kk * 64 + kgb);
  off ^= (unsigned)((arow & 7) << 4);
  return *(const half8*)((const char*)stg + off);
}

// ---------------------------------------------------------------------------
__global__ __launch_bounds__(TPB, 1) void lstm_fused(
    const float* __restrict__ Whh0,
    const float* __restrict__ bih0, const float* __restrict__ bhh0,
    const float* __restrict__ Wih1,
    const float* __restrict__ Whh1,
    const float* __restrict__ bih1, const float* __restrict__ bhh1,
    const int* __restrict__ x,
    const float* __restrict__ Hst,
    const float* __restrict__ Cst,
    float* __restrict__ y1out,
    float* __restrict__ outh,
    float* __restrict__ outc)
{
  const int tid = threadIdx.x;
  const int lane = tid & 63;
  const int w = tid >> 6;

  __shared__ _Float16 stage_s[BH];       // 64 KB
  __shared__ float gates_s[32 * 132];    // 16.5 KB -> ~81KB total -> 1 block/CU
  __shared__ unsigned sh_xcc, sh_rank;

  if (tid == 0) {
    unsigned xc;
    asm volatile("s_getreg_b32 %0, hwreg(HW_REG_XCC_ID)" : "=s"(xc));
    xc &= 7u;
    sh_xcc = xc;
    sh_rank = __hip_atomic_fetch_add(&g_xcdcnt[xc * 32], 1u,
                                     __ATOMIC_RELAXED, __HIP_MEMORY_SCOPE_AGENT);
  }
  __syncthreads();
  const unsigned xcc = sh_xcc;
  const unsigned rank = sh_rank;

  const int kgrp = (lane >> 4) * 8;      // halfs
  const int kgb = (lane >> 4) * 16;      // bytes

  // =========================== recurrence role ===========================
  if (xcc <= 1u && rank < 32u) {
    const bool isL1 = (xcc == 1u);
    const int jbase = (int)rank * 32;    // this block's 32 hidden dims
    const float* Whh = isL1 ? Whh1 : Whh0;
    const float* bih = isL1 ? bih1 : bih0;
    const float* bhh = isL1 ? bhh1 : bhh0;
    _Float16* yloc = isL1 ? g_y1loc : g_y0loc;
    unsigned* slots = isL1 ? g_slot1 : g_slot0;

    // W_hh fragments -> VGPRs (wave w == gate w; two 16-dim N-tiles)
    half8 wf0[32], wf1[32];
    {
      const int rw0 = w * H_ + jbase + (lane & 15);
      const int rw1 = rw0 + 16;
#pragma unroll
      for (int kk = 0; kk < 32; ++kk) {
        wf0[kk] = load8_cvt(Whh + (size_t)rw0 * H_ + kk * 32 + kgrp);
        wf1[kk] = load8_cvt(Whh + (size_t)rw1 * H_ + kk * 32 + kgrp);
      }
    }

    const int b = tid >> 3;
    const int d0 = (tid & 7) * 4;
    const int j0 = jbase + d0;

    float bs[4][4];
#pragma unroll
    for (int g = 0; g < 4; ++g)
#pragma unroll
      for (int dd = 0; dd < 4; ++dd)
        bs[g][dd] = bih[g * H_ + j0 + dd] + bhh[g * H_ + j0 + dd];

    float cc[4], hf[4];
    {
      const float4 hi = *(const float4*)&Hst[(isL1 ? BH : 0) + b * H_ + j0];
      const float4 ci = *(const float4*)&Cst[(isL1 ? BH : 0) + b * H_ + j0];
      cc[0] = ci.x; cc[1] = ci.y; cc[2] = ci.z; cc[3] = ci.w;
      hf[0] = hi.x; hf[1] = hi.y; hf[2] = hi.z; hf[3] = hi.w;
    }
    union { _Float16 h[4]; ull u; } pk;
#pragma unroll
    for (int dd = 0; dd < 4; ++dd) pk.h[dd] = (_Float16)hf[dd];
    ull hv_keep = pk.u;
    *(ull*)&yloc[(size_t)b * H_ + j0] = hv_keep;     // slot 0 (plain, local L2)

    __syncthreads();                                  // drain slot-0 stores
    if (tid == 0) st_ag(&slots[rank * 8], 1u);        // announce round 1

    for (int t = 0; t < T_; ++t) {
      // input-side gates: prefetch BEFORE the wait when legal
      ull gxu[4];
      if (!isL1) {
        const int xv = x[t * B_ + b];
        const _Float16* gp = g_Wt + (size_t)xv * GX + j0;
#pragma unroll
        for (int g = 0; g < 4; ++g) gxu[g] = *(const ull*)(gp + g * H_);
      } else if (t & (TC - 1)) {
        // ggx[t] valid since this chunk's gate (sc1 8B loads)
        const size_t gbase = (((size_t)t * B_ + b) * GX + j0) >> 2;
#pragma unroll
        for (int g = 0; g < 4; ++g) gxu[g] = ld_ag64(&g_ggx[gbase + (size_t)(g * H_ >> 2)]);
      }

      // ---- wait: all 32 peers at round t+1 (+ chunk gate for L1) ----
      const unsigned r = (unsigned)(t + 1);
      if (isL1 && (t & (TC - 1)) == 0)
        slot_wait(slots, r, &g_chunk[(t / TC) * 32], 128u);
      else
        slot_wait(slots, r, nullptr, 0u);

      if (!isL1) {
        // publish progress (off-path) + previous h slot for helpers
        if (rank == 0u && tid == 0 && t >= 1) st_ag(g_l0prog, (unsigned)(t - 1));
        st_ag64(&g_y0pub[((size_t)t * BH + b * H_ + j0) >> 2], hv_keep);
      } else if ((t & (TC - 1)) == 0) {
        const size_t gbase = (((size_t)t * B_ + b) * GX + j0) >> 2;
#pragma unroll
        for (int g = 0; g < 4; ++g) gxu[g] = ld_ag64(&g_ggx[gbase + (size_t)(g * H_ >> 2)]);
      }

      // stage h(t) 64KB -> LDS (plain loads, same-XCD L2 hits)
      stage_h(stage_s, yloc + (size_t)t * BH, w);
      __syncthreads();

      // MFMA: 2 M-tiles x 2 N-tiles x K=1024
      f32x4 a00 = {0.f,0.f,0.f,0.f}, a01 = {0.f,0.f,0.f,0.f};
      f32x4 a10 = {0.f,0.f,0.f,0.f}, a11 = {0.f,0.f,0.f,0.f};
#pragma unroll
      for (int kk = 0; kk < 32; ++kk) {
        const half8 A0 = lds_a(stage_s, (lane & 15), kk, kgb);
        const half8 A1 = lds_a(stage_s, 16 + (lane & 15), kk, kgb);
        a00 = __builtin_amdgcn_mfma_f32_16x16x32_f16(A0, wf0[kk], a00, 0, 0, 0);
        a01 = __builtin_amdgcn_mfma_f32_16x16x32_f16(A0, wf1[kk], a01, 0, 0, 0);
        a10 = __builtin_amdgcn_mfma_f32_16x16x32_f16(A1, wf0[kk], a10, 0, 0, 0);
        a11 = __builtin_amdgcn_mfma_f32_16x16x32_f16(A1, wf1[kk], a11, 0, 0, 0);
      }

      // gate exchange: rows = batch (M), cols = gate w * 32 + local dim (N)
      {
        const int colb = w * 32 + (lane & 15);
        const int rowb = (lane >> 4) * 4;
#pragma unroll
        for (int r2 = 0; r2 < 4; ++r2) {
          gates_s[(rowb + r2) * 132 + colb]           = a00[r2];
          gates_s[(rowb + r2) * 132 + colb + 16]      = a01[r2];
          gates_s[(16 + rowb + r2) * 132 + colb]      = a10[r2];
          gates_s[(16 + rowb + r2) * 132 + colb + 16] = a11[r2];
        }
      }
      __syncthreads();

      // activation (float4 reads: 4 vector loads instead of 16 scalar)
      float4 G[4];
#pragma unroll
      for (int g = 0; g < 4; ++g)
        G[g] = *(const float4*)&gates_s[b * 132 + g * 32 + d0];
#pragma unroll
      for (int dd = 0; dd < 4; ++dd) {
        const float gi = ((const float*)&G[0])[dd] + (float)((const _Float16*)&gxu[0])[dd] + bs[0][dd];
        const float gf = ((const float*)&G[1])[dd] + (float)((const _Float16*)&gxu[1])[dd] + bs[1][dd];
        const float gg = ((const float*)&G[2])[dd] + (float)((const _Float16*)&gxu[2])[dd] + bs[2][dd];
        const float go = ((const float*)&G[3])[dd] + (float)((const _Float16*)&gxu[3])[dd] + bs[3][dd];
        const float iv = sigmf(gi), fv = sigmf(gf);
        const float gv = tanhf_(gg), ov = sigmf(go);
        cc[dd] = fv * cc[dd] + iv * gv;
        hf[dd] = ov * tanhf_(cc[dd]);
        pk.h[dd] = (_Float16)hf[dd];
      }
      hv_keep = pk.u;
      *(ull*)&yloc[(size_t)(t + 1) * BH + b * H_ + j0] = hv_keep;   // plain/local
      if (isL1)
        *(float4*)&y1out[(size_t)t * BH + b * H_ + j0] =
            make_float4(hf[0], hf[1], hf[2], hf[3]);

      __syncthreads();                      // drain stores (incl. sc1 publish)
      if (tid == 0) st_ag(&slots[rank * 8], (unsigned)(t + 2));
    }

    // L0 epilogue: publish final slot, announce, rank0 aggregates l0prog=T
    if (!isL1) {
      st_ag64(&g_y0pub[((size_t)T_ * BH + b * H_ + j0) >> 2], hv_keep);
      __syncthreads();
      if (tid == 0) st_ag(&g_slot0[rank * 8], (unsigned)(T_ + 2));
      if (rank == 0u) {
        slot_wait(g_slot0, (unsigned)(T_ + 2), nullptr, 0u);
        if (tid == 0) st_ag(g_l0prog, (unsigned)T_);
      }
    }

    *(float4*)&outh[(isL1 ? BH : 0) + b * H_ + j0] = make_float4(hf[0], hf[1], hf[2], hf[3]);
    *(float4*)&outc[(isL1 ? BH : 0) + b * H_ + j0] = make_float4(cc[0], cc[1], cc[2], cc[3]);
    return;
  }

  // ============================ helper role ==============================
  // Any non-recurrence block takes a global ticket; first 128 work.
  __shared__ unsigned sh_hid;
  if (tid == 0) sh_hid = add_ag(g_heltick);
  __syncthreads();
  const unsigned hid = sh_hid;
  if (hid >= 128u) return;

  half8 wih0[32], wih1[32];
  {
    const int rw0 = (int)hid * 32 + (lane & 15);
    const int rw1 = rw0 + 16;
#pragma unroll
    for (int kk = 0; kk < 32; ++kk) {
      wih0[kk] = load8_cvt(Wih1 + (size_t)rw0 * H_ + kk * 32 + kgrp);
      wih1[kk] = load8_cvt(Wih1 + (size_t)rw1 * H_ + kk * 32 + kgrp);
    }
  }
  const int cg0 = (int)hid * 32 + (lane & 15);
  const int cg1 = cg0 + 16;
  short* ggx_s = (short*)g_ggx;

  for (int c = 0; c < NCH; ++c) {
    if (tid == 0) {
      int guard = 0;
      while (ld_ag(g_l0prog) < (unsigned)(c * TC + TC)) {
        __builtin_amdgcn_s_sleep(4);
        if (++guard > GUARD) break;
      }
    }
    __syncthreads();
    const int t0 = c * TC;

#pragma unroll 1
    for (int mt = 0; mt < 4; ++mt) {
      const int arow = w * 64 + mt * 16 + (lane & 15);        // 0..255
      const size_t abase = (((size_t)(t0 + (arow >> 5) + 1) * BH) +
                            (size_t)(arow & 31) * H_ + kgrp) >> 2;   // ull units
      f32x4 e0 = {0.f,0.f,0.f,0.f}, e1 = {0.f,0.f,0.f,0.f};
#pragma unroll
      for (int kk = 0; kk < 32; ++kk) {
        union { ull u[2]; half8 v; } a;
        a.u[0] = ld_ag64(&g_y0pub[abase + kk * 8]);
        a.u[1] = ld_ag64(&g_y0pub[abase + kk * 8 + 1]);
        e0 = __builtin_amdgcn_mfma_f32_16x16x32_f16(a.v, wih0[kk], e0, 0, 0, 0);
        e1 = __builtin_amdgcn_mfma_f32_16x16x32_f16(a.v, wih1[kk], e1, 0, 0, 0);
      }
      const int mrow = w * 64 + mt * 16 + (lane >> 4) * 4;
#pragma unroll
      for (int r = 0; r < 4; ++r) {
        const int m = mrow + r;
        const int tt = t0 + (m >> 5);
        const int bb = m & 31;
        const _Float16 v0 = (_Float16)e0[r];    // raw GEMM; bias added by L1
        const _Float16 v1 = (_Float16)e1[r];
        __hip_atomic_store(&ggx_s[((size_t)tt * B_ + bb) * GX + cg0],
                           __builtin_bit_cast(short, v0),
                           __ATOMIC_RELAXED, __HIP_MEMORY_SCOPE_AGENT);
        __hip_atomic_store(&ggx_s[((size_t)tt * B_ + bb) * GX + cg1],
                           __builtin_bit_cast(short, v1),
                           __ATOMIC_RELAXED, __HIP_MEMORY_SCOPE_AGENT);
      }
    }
    __syncthreads();                       // drain sc1 stores
    if (tid == 0) add_ag(&g_chunk[c * 32]);
  }
}

// ---------------------------------------------------------------------------
extern "C" void kernel_launch(void* const* d_in, const int* in_sizes, int n_in,
                              void* d_out, int out_size, void* d_ws, size_t ws_size,
                              hipStream_t stream) {
  (void)in_sizes; (void)n_in; (void)d_ws; (void)ws_size; (void)out_size;

  const int*   x    = (const int*)  d_in[0];
  const float* Hst  = (const float*)d_in[1];
  const float* Cst  = (const float*)d_in[2];
  const float* Wih0 = (const float*)d_in[3];
  const float* Whh0 = (const float*)d_in[4];
  const float* bih0 = (const float*)d_in[5];
  const float* bhh0 = (const float*)d_in[6];
  const float* Wih1 = (const float*)d_in[7];
  const float* Whh1 = (const float*)d_in[8];
  const float* bih1 = (const float*)d_in[9];
  const float* bhh1 = (const float*)d_in[10];

  float* out   = (float*)d_out;
  float* y1out = out;
  float* outh  = out + (size_t)T_ * BH;
  float* outc  = outh + (size_t)2 * BH;

  hipLaunchKernelGGL(init_bar_k, dim3(1), dim3(1024), 0, stream);
  hipLaunchKernelGGL(transpose_wih0, dim3(8192), dim3(256), 0, stream, Wih0);
  hipLaunchKernelGGL(lstm_fused, dim3(256), dim3(TPB), 0, stream,
                     Whh0, bih0, bhh0, Wih1, Whh1, bih1, bhh1,
                     x, Hst, Cst, y1out, outh, outc);
}